// Round 1
// baseline (127.243 us; speedup 1.0000x reference)
//
#include <hip/hip_runtime.h>

// Problem constants (from reference setup_inputs)
constexpr int cB = 32, cC = 6, cT = 64;
constexpr int cK = 8, cN = 128;
constexpr int cS = 32, cP = 64;
constexpr int NSEG = cK * (cN - 1);   // 1016 boundary segments per batch
constexpr int NCL  = cS * cP;         // 2048 centerline points per batch
constexpr float F_EPS = 1e-6f;
constexpr float F_THRESHOLD = 0.5f;

__global__ __launch_bounds__(256) void offroad_kernel(
    const float* __restrict__ points,         // (B, C, T, 2)
    const float* __restrict__ road_boundary,  // (B, K, N, 2)
    const float* __restrict__ centerlines,    // (B, S, P, 2)
    float* __restrict__ out)                  // (B, C)
{
    __shared__ float4 s_seg[NSEG];   // (ax, ay, dx, dy)
    __shared__ float  s_inv[NSEG];   // 1 / (|d|^2 + EPS)
    __shared__ float2 s_cl[NCL];     // centerline points
    __shared__ float  s_part[4];     // per-wave partial sums

    const int blk = blockIdx.x;      // 0 .. B*C-1
    const int b = blk / cC;
    const int c = blk % cC;
    const int tid = threadIdx.x;

    // ---- Stage boundary segments into LDS ----
    const float* rb = road_boundary + (size_t)b * cK * cN * 2;
    for (int s = tid; s < NSEG; s += 256) {
        int k = s / (cN - 1);
        int n = s - k * (cN - 1);
        const float* p0 = rb + (k * cN + n) * 2;
        float ax = p0[0], ay = p0[1];
        float dx = p0[2] - ax, dy = p0[3] - ay;
        s_seg[s] = make_float4(ax, ay, dx, dy);
        s_inv[s] = 1.0f / (dx * dx + dy * dy + F_EPS);
    }
    // ---- Stage centerlines into LDS ----
    const float* cl = centerlines + (size_t)b * NCL * 2;
    for (int i = tid; i < NCL; i += 256) {
        s_cl[i] = make_float2(cl[2 * i], cl[2 * i + 1]);
    }
    __syncthreads();

    // 4 threads cooperate per point: t = point index, q = slice
    const int t = tid >> 2;
    const int q = tid & 3;
    const size_t pbase = (((size_t)b * cC + c) * cT + t) * 2;
    const float px = points[pbase + 0];
    const float py = points[pbase + 1];

    // ---- 1. min point-to-segment distance (squared) ----
    float min_d2 = 3.4e38f;
    for (int s = q; s < NSEG; s += 4) {
        float4 sg = s_seg[s];
        float v1x = px - sg.x, v1y = py - sg.y;
        float dot = v1x * sg.z + v1y * sg.w;
        float proj = dot * s_inv[s];
        proj = fminf(fmaxf(proj, 0.0f), 1.0f);
        float ex = v1x - sg.z * proj;   // p - (a + d*proj)
        float ey = v1y - sg.w * proj;
        float d2 = ex * ex + ey * ey;
        min_d2 = fminf(min_d2, d2);
    }

    // ---- 2. centerline argmin (first-index tie-break, matches jnp.argmin) ----
    float best_d2 = 3.4e38f;
    int best_i = 0x7fffffff;
    for (int i = q; i < NCL; i += 4) {
        float2 cp = s_cl[i];
        float dx = px - cp.x, dy = py - cp.y;
        float d2 = dx * dx + dy * dy;
        if (d2 < best_d2) { best_d2 = d2; best_i = i; }
    }
    #pragma unroll
    for (int off = 1; off <= 2; off <<= 1) {
        float od2 = __shfl_xor(best_d2, off);
        int   oi  = __shfl_xor(best_i, off);
        if (od2 < best_d2 || (od2 == best_d2 && oi < best_i)) {
            best_d2 = od2; best_i = oi;
        }
    }
    const float2 cc = s_cl[best_i];   // all 4 lanes agree

    // ---- 3. segment intersection test (point -> closest centerline pt) ----
    const float dax = cc.x - px, day = cc.y - py;   // da = a2 - a1
    int hit = 0;
    for (int s = q; s < NSEG; s += 4) {
        float4 sg = s_seg[s];
        float dpx = px - sg.x, dpy = py - sg.y;     // dp = a1 - b1
        float dadb = dax * sg.w - day * sg.z;       // cross(da, db)
        float inv = 1.0f / (dadb + F_EPS);
        float tt = (dax * dpy - day * dpx) * inv;   // cross(da, dp)/(dadb+EPS)
        float uu = (sg.z * dpy - sg.w * dpx) * inv; // cross(db, dp)/(dadb+EPS)
        hit |= (tt >= 0.0f && tt <= 1.0f && uu >= 0.0f && uu <= 1.0f) ? 1 : 0;
    }

    // ---- reduce min_d2 / hit across the 4 cooperating lanes ----
    #pragma unroll
    for (int off = 1; off <= 2; off <<= 1) {
        min_d2 = fminf(min_d2, __shfl_xor(min_d2, off));
        hit |= __shfl_xor(hit, off);
    }

    float md = sqrtf(min_d2);
    float sd = hit ? md : -md;                 // inside (no hit) -> negative
    float val = fmaxf(sd + F_THRESHOLD, 0.0f); // relu(min_dist + THRESHOLD)
    if (q != 0) val = 0.0f;                    // count each point once

    // ---- sum over T within the block ----
    #pragma unroll
    for (int off = 32; off >= 1; off >>= 1)
        val += __shfl_down(val, off);
    const int wave = tid >> 6;
    if ((tid & 63) == 0) s_part[wave] = val;
    __syncthreads();
    if (tid == 0)
        out[blk] = s_part[0] + s_part[1] + s_part[2] + s_part[3];
}

extern "C" void kernel_launch(void* const* d_in, const int* in_sizes, int n_in,
                              void* d_out, int out_size, void* d_ws, size_t ws_size,
                              hipStream_t stream) {
    const float* points      = (const float*)d_in[0];
    const float* boundary    = (const float*)d_in[1];
    const float* centerlines = (const float*)d_in[2];
    float* out = (float*)d_out;
    offroad_kernel<<<cB * cC, 256, 0, stream>>>(points, boundary, centerlines, out);
}

// Round 2
// 86.316 us; speedup vs baseline: 1.4741x; 1.4741x over previous
//
#include <hip/hip_runtime.h>

// Problem constants (from reference setup_inputs)
constexpr int cB = 32, cC = 6, cT = 64;
constexpr int cK = 8, cN = 128;
constexpr int cS = 32, cP = 64;
constexpr int NSEG = cK * (cN - 1);   // 1016 boundary segments per batch
constexpr int NSEG_PAD = 1024;        // padded for uniform trip counts
constexpr int NCL  = cS * cP;         // 2048 centerline points per batch
constexpr int G = 4;                  // T-splits per (b,c): 16 points per block
constexpr int LPP = 16;               // lanes per point
constexpr float F_EPS = 1e-6f;
constexpr float F_THRESHOLD = 0.5f;

__global__ __launch_bounds__(256) void offroad_kernel(
    const float* __restrict__ points,         // (B, C, T, 2)
    const float* __restrict__ road_boundary,  // (B, K, N, 2)
    const float* __restrict__ centerlines,    // (B, S, P, 2)
    float* __restrict__ out)                  // (B, C), pre-zeroed
{
    __shared__ float4 s_seg[NSEG_PAD];   // (ax, ay, dx, dy)
    __shared__ float  s_inv[NSEG_PAD];   // 1 / (|d|^2 + EPS)
    __shared__ float4 s_cl4[NCL / 2];    // centerline points, 2 per float4
    __shared__ float  s_part[4];         // per-wave partial sums

    const int blk = blockIdx.x;          // 0 .. B*C*G-1
    const int g  = blk & (G - 1);
    const int bc = blk >> 2;             // b*C + c
    const int b  = bc / cC;
    const int tid = threadIdx.x;

    // ---- Stage boundary segments into LDS (padded) ----
    const float* rb = road_boundary + (size_t)b * cK * cN * 2;
    for (int s = tid; s < NSEG_PAD; s += 256) {
        if (s < NSEG) {
            int k = s / (cN - 1);
            int n = s - k * (cN - 1);
            const float* p0 = rb + (k * cN + n) * 2;
            float ax = p0[0], ay = p0[1];
            float dx = p0[2] - ax, dy = p0[3] - ay;
            s_seg[s] = make_float4(ax, ay, dx, dy);
            s_inv[s] = 1.0f / (dx * dx + dy * dy + F_EPS);
        } else {
            s_seg[s] = make_float4(1e18f, 1e18f, 0.0f, 0.0f);  // -> huge d2
            s_inv[s] = 0.0f;
        }
    }
    // ---- Stage centerlines into LDS (float4 = 2 points) ----
    const float4* cl4 = (const float4*)(centerlines + (size_t)b * NCL * 2);
    for (int i = tid; i < NCL / 2; i += 256) s_cl4[i] = cl4[i];
    __syncthreads();

    // 16 lanes cooperate per point: 16 points per block
    const int t = (g << 4) | (tid >> 4);   // global point index in [0, 64)
    const int q = tid & (LPP - 1);
    const size_t pbase = (((size_t)bc) * cT + t) * 2;
    const float px = points[pbase + 0];
    const float py = points[pbase + 1];

    // ---- 1. min point-to-segment distance (squared), 64 uniform iters ----
    float min_d2 = 3.4e38f;
    #pragma unroll 4
    for (int s = q; s < NSEG_PAD; s += LPP) {
        float4 sg = s_seg[s];
        float v1x = px - sg.x, v1y = py - sg.y;
        float dot = v1x * sg.z + v1y * sg.w;
        float proj = dot * s_inv[s];
        proj = fminf(fmaxf(proj, 0.0f), 1.0f);
        float ex = v1x - sg.z * proj;
        float ey = v1y - sg.w * proj;
        float d2 = ex * ex + ey * ey;
        min_d2 = fminf(min_d2, d2);
    }

    // ---- 2. centerline argmin (first-index tie-break), 64 iters x 2 pts ----
    float best_d2 = 3.4e38f;
    int best_i = 0x7fffffff;
    #pragma unroll 4
    for (int j = q; j < NCL / 2; j += LPP) {
        float4 cp = s_cl4[j];
        float dxa = px - cp.x, dya = py - cp.y;
        float d2a = dxa * dxa + dya * dya;
        float dxb = px - cp.z, dyb = py - cp.w;
        float d2b = dxb * dxb + dyb * dyb;
        int   ia = 2 * j;
        float dmin = d2a; int imin = ia;
        if (d2b < d2a) { dmin = d2b; imin = ia + 1; }  // prefer lower idx on tie
        if (dmin < best_d2 || (dmin == best_d2 && imin < best_i)) {
            best_d2 = dmin; best_i = imin;
        }
    }
    #pragma unroll
    for (int off = 1; off <= 8; off <<= 1) {
        float od2 = __shfl_xor(best_d2, off);
        int   oi  = __shfl_xor(best_i, off);
        if (od2 < best_d2 || (od2 == best_d2 && oi < best_i)) {
            best_d2 = od2; best_i = oi;
        }
    }
    const float2* s_cl2 = (const float2*)s_cl4;
    const float2 cc = s_cl2[best_i];     // all 16 lanes agree

    // ---- 3. segment intersection (point -> closest centerline pt) ----
    const float dax = cc.x - px, day = cc.y - py;   // da = a2 - a1
    int hit = 0;
    #pragma unroll 4
    for (int s = q; s < NSEG_PAD; s += LPP) {
        float4 sg = s_seg[s];
        float dpx = px - sg.x, dpy = py - sg.y;     // dp = a1 - b1
        float dadb = dax * sg.w - day * sg.z;       // cross(da, db)
        float inv = 1.0f / (dadb + F_EPS);
        float tt = (dax * dpy - day * dpx) * inv;   // cross(da, dp)/(dadb+EPS)
        float uu = (sg.z * dpy - sg.w * dpx) * inv; // cross(db, dp)/(dadb+EPS)
        bool inb = (tt >= 0.0f) & (tt <= 1.0f) & (uu >= 0.0f) & (uu <= 1.0f);
        hit |= (int)((s < NSEG) & inb);
    }

    // ---- reduce min_d2 / hit across the 16 cooperating lanes ----
    #pragma unroll
    for (int off = 1; off <= 8; off <<= 1) {
        min_d2 = fminf(min_d2, __shfl_xor(min_d2, off));
        hit |= __shfl_xor(hit, off);
    }

    float md = sqrtf(min_d2);
    float sd = hit ? md : -md;                 // inside (no hit) -> negative
    float val = fmaxf(sd + F_THRESHOLD, 0.0f); // relu(min_dist + THRESHOLD)
    if (q != 0) val = 0.0f;                    // count each point once

    // ---- sum within the block, one atomic per block ----
    #pragma unroll
    for (int off = 32; off >= 1; off >>= 1)
        val += __shfl_down(val, off);
    const int wave = tid >> 6;
    if ((tid & 63) == 0) s_part[wave] = val;
    __syncthreads();
    if (tid == 0)
        atomicAdd(&out[bc], s_part[0] + s_part[1] + s_part[2] + s_part[3]);
}

extern "C" void kernel_launch(void* const* d_in, const int* in_sizes, int n_in,
                              void* d_out, int out_size, void* d_ws, size_t ws_size,
                              hipStream_t stream) {
    const float* points      = (const float*)d_in[0];
    const float* boundary    = (const float*)d_in[1];
    const float* centerlines = (const float*)d_in[2];
    float* out = (float*)d_out;
    hipMemsetAsync(out, 0, (size_t)out_size * sizeof(float), stream);
    offroad_kernel<<<cB * cC * G, 256, 0, stream>>>(points, boundary, centerlines, out);
}